// Round 1
// baseline (3913.893 us; speedup 1.0000x reference)
//
#include <hip/hip_runtime.h>
#include <math.h>

// Problem constants: B=2, Cin=Cout=32, D=H=W=32, 3x3x3 conv pad 1, 8 directions.
#define NB 2
#define NC 32
#define DD 32
#define VOL (DD*DD*DD)            // 32768
#define WCO 864                   // Cin*27 floats per output channel
#define WDIR (NC*NC*27)           // 27648 floats per direction per gate
#define BUF_ELEMS (NB*VOL*NC)     // 2097152 floats per channel-last buffer

// ---------------------------------------------------------------------------
// Stage weights for one input channel ci: ws layout [g][co][tap] (g*864+co*27+tap)
__device__ __forceinline__ void stage_w(const float* __restrict__ Wh,
                                        const float* __restrict__ Wz,
                                        const float* __restrict__ Ws,
                                        float* wsb, int ci, int tid)
{
    for (int t = tid; t < 3*NC*27; t += 256) {
        int g   = t / 864;
        int rem = t - g*864;
        int co2 = rem / 27;
        int tap = rem - co2*27;
        const float* W = (g == 0) ? Wh : (g == 1) ? Wz : Ws;
        wsb[t] = W[co2*WCO + ci*27 + tap];   // wsb[t] == [g][co2][tap]
    }
}

// ---------------------------------------------------------------------------
// Direct conv, 3 gates fused. Block per (b,i,j); 256 threads = co(32, fast) x kq(8).
// Outputs channel-last (b,i,j,k,c) for coalesced scan reads.
__global__ __launch_bounds__(256) void conv3_gates(
    const float* __restrict__ x,
    const float* __restrict__ Wh, const float* __restrict__ Wz, const float* __restrict__ Ws,
    const float* __restrict__ bh, const float* __restrict__ bz, const float* __restrict__ bs,
    float* __restrict__ outh, float* __restrict__ outz, float* __restrict__ outs)
{
    __shared__ __align__(16) float xs[NC*9*36];   // x halo tile: [ci][r(3x3)][kk 0..35], 41.5 KB
    __shared__ __align__(16) float ws[2][3*NC*27]; // double-buffered weights for one ci, 2x10.1 KB

    const int tid = threadIdx.x;
    const int co  = tid & 31;
    const int kq  = tid >> 5;

    const int blk = blockIdx.x;
    const int b = blk >> 10;
    const int i = (blk >> 5) & 31;
    const int j = blk & 31;

    // ---- stage x tile (zero-padded), coalesced along k ----
    for (int t = tid; t < NC*9*36; t += 256) {
        int ci  = t / (9*36);
        int rem = t - ci*(9*36);
        int r   = rem / 36;
        int kk  = rem - r*36;
        int k   = kk - 1;
        int ii  = i + (r/3) - 1;
        int jj  = j + (r%3) - 1;
        float v = 0.0f;
        if ((unsigned)ii < 32u && (unsigned)jj < 32u && (unsigned)k < 32u)
            v = x[(((b*NC + ci)*DD + ii)*DD + jj)*DD + k];
        xs[t] = v;   // layout matches ci*324 + r*36 + kk
    }
    stage_w(Wh, Wz, Ws, ws[0], 0, tid);
    __syncthreads();

    float acc0[4], acc1[4], acc2[4];
    const float b0 = bh[co], b1 = bz[co], b2 = bs[co];
    #pragma unroll
    for (int t = 0; t < 4; ++t) { acc0[t] = b0; acc1[t] = b1; acc2[t] = b2; }

    for (int ci = 0; ci < NC; ++ci) {
        const int cur = ci & 1;
        if (ci + 1 < NC) stage_w(Wh, Wz, Ws, ws[cur ^ 1], ci + 1, tid);

        const float* xrow = &xs[ci*324 + kq*4];
        const float* wb   = ws[cur];
        #pragma unroll
        for (int r = 0; r < 9; ++r) {
            const float4 xa = *(const float4*)(xrow + r*36);
            const float2 xb = *(const float2*)(xrow + r*36 + 4);
            const float xv[6] = {xa.x, xa.y, xa.z, xa.w, xb.x, xb.y};
            const float* w0 = wb +          co*27 + r*3;
            const float* w1 = wb +  864   + co*27 + r*3;
            const float* w2 = wb + 2*864  + co*27 + r*3;
            #pragma unroll
            for (int dk = 0; dk < 3; ++dk) {
                const float wh_ = w0[dk], wz_ = w1[dk], ws_ = w2[dk];
                #pragma unroll
                for (int t = 0; t < 4; ++t) {
                    acc0[t] = fmaf(wh_, xv[dk + t], acc0[t]);
                    acc1[t] = fmaf(wz_, xv[dk + t], acc1[t]);
                    acc2[t] = fmaf(ws_, xv[dk + t], acc2[t]);
                }
            }
        }
        __syncthreads();   // staging of next buffer complete; prev reads done
    }

    // ---- store channel-last: [b][i][j][k][c] ----
    const int base = ((b*DD + i)*DD + j)*DD*NC + co;
    #pragma unroll
    for (int t = 0; t < 4; ++t) {
        const int k = kq*4 + t;
        outh[base + k*NC] = acc0[t];
        outz[base + k*NC] = 1.0f / (1.0f + expf(-acc1[t]));
        outs[base + k*NC] = 1.0f / (1.0f + expf(-acc2[t]));
    }
}

// ---------------------------------------------------------------------------
// Diagonal GRU scan for direction (di,dj,dk), accumulating o*s into acc.
// Chains partition the volume; lane = channel (coalesced 128B per step).
// Canonical (+1,+1,+1) chain starts: min(i,j,k)==0 -> 2977 chains per batch.
__global__ __launch_bounds__(256) void gru_scan(
    const float* __restrict__ bufh, const float* __restrict__ bufz,
    const float* __restrict__ bufs, float* __restrict__ acc,
    const float* __restrict__ h0, int di, int dj, int dk)
{
    const int c    = threadIdx.x & 31;
    const int slot = threadIdx.x >> 5;
    const int cid  = blockIdx.x * 8 + slot;
    if (cid >= 2977) return;
    const int b = blockIdx.y;

    int ic, jc, kc;
    if (cid < 1024)      { ic = 0;                 jc = cid >> 5;           kc = cid & 31; }
    else if (cid < 2016) { int t = cid - 1024;     ic = 1 + (t >> 5);       jc = 0; kc = t & 31; }
    else                 { int t = cid - 2016;     int q = t / 31;
                           ic = 1 + q;             jc = 1 + (t - q*31);     kc = 0; }

    int mx = ic > jc ? ic : jc; if (kc > mx) mx = kc;
    const int L  = 32 - mx;
    const int i0 = (di > 0) ? ic : 31 - ic;
    const int j0 = (dj > 0) ? jc : 31 - jc;
    const int k0 = (dk > 0) ? kc : 31 - kc;
    const int step = di*(DD*DD*NC) + dj*(DD*NC) + dk*NC;

    int p = b*(VOL*NC) + i0*(DD*DD*NC) + j0*(DD*NC) + k0*NC + c;
    float prev = h0[c];
    for (int s = 0; s < L; ++s) {
        const float zv = bufz[p];
        const float hv = bufh[p];
        const float sv = bufs[p];
        const float o  = zv*hv + (1.0f - zv)*prev;
        acc[p] += o * sv;
        prev = o;
        p += step;
    }
}

// ---------------------------------------------------------------------------
// (b,i,j,k,c) -> (b,c,i,j,k) transpose into d_out.
__global__ __launch_bounds__(256) void transpose_out(
    const float* __restrict__ acc, float* __restrict__ out)
{
    __shared__ float tl[32][33];
    const int blk = blockIdx.x;
    const int b = blk >> 10;
    const int i = (blk >> 5) & 31;
    const int j = blk & 31;

    const int c  = threadIdx.x & 31;
    const int kq = threadIdx.x >> 5;
    const int base = ((b*DD + i)*DD + j)*DD*NC;
    #pragma unroll
    for (int t = 0; t < 4; ++t) {
        const int k = kq*4 + t;
        tl[k][c] = acc[base + k*NC + c];
    }
    __syncthreads();

    const int k2 = threadIdx.x & 31;
    const int cq = threadIdx.x >> 5;
    const int obase = b*(NC*VOL) + i*(DD*DD) + j*DD;
    #pragma unroll
    for (int t = 0; t < 4; ++t) {
        const int co = cq*4 + t;
        out[obase + co*VOL + k2] = tl[k2][co];
    }
}

// ---------------------------------------------------------------------------
extern "C" void kernel_launch(void* const* d_in, const int* in_sizes, int n_in,
                              void* d_out, int out_size, void* d_ws, size_t ws_size,
                              hipStream_t stream)
{
    const float* x  = (const float*)d_in[0];
    const float* Wh = (const float*)d_in[1];
    const float* bh = (const float*)d_in[2];
    const float* Wz = (const float*)d_in[3];
    const float* bz = (const float*)d_in[4];
    const float* Ws = (const float*)d_in[5];
    const float* bs = (const float*)d_in[6];
    const float* h0 = (const float*)d_in[7];
    float* out = (float*)d_out;

    float* bufh = (float*)d_ws;                  // 8 MB each, channel-last
    float* bufz = bufh + BUF_ELEMS;
    float* bufs = bufz + BUF_ELEMS;
    float* acc  = bufs + BUF_ELEMS;              // total 32 MB of d_ws

    hipMemsetAsync(acc, 0, BUF_ELEMS*sizeof(float), stream);

    for (int n = 0; n < 8; ++n) {
        const int di = (n & 4) ? 1 : -1;
        const int dj = (n & 2) ? 1 : -1;
        const int dk = (n & 1) ? 1 : -1;
        conv3_gates<<<NB*DD*DD, 256, 0, stream>>>(
            x, Wh + n*WDIR, Wz + n*WDIR, Ws + n*WDIR,
            bh + n*NC, bz + n*NC, bs + n*NC,
            bufh, bufz, bufs);
        gru_scan<<<dim3((2977 + 7)/8, NB), 256, 0, stream>>>(
            bufh, bufz, bufs, acc, h0 + n*NC, di, dj, dk);
    }
    transpose_out<<<NB*DD*DD, 256, 0, stream>>>(acc, out);
}

// Round 2
// 494.302 us; speedup vs baseline: 7.9180x; 7.9180x over previous
//
#include <hip/hip_runtime.h>
#include <hip/hip_bf16.h>
#include <math.h>

// Problem constants: B=2, Cin=Cout=32, D=H=W=32, 3x3x3 conv pad 1, 8 directions.
#define NB 2
#define NC 32
#define DD 32
#define VOL (DD*DD*DD)            // 32768
#define WCO 864                   // Cin*27 floats per output channel (fp32 weights)
#define WDIR (NC*NC*27)           // 27648 floats per direction per gate
#define BUF_ELEMS (NB*VOL*NC)     // 2097152 elements per channel-last buffer
#define WT_DIR (27*96*32)         // 82944 bf16 per direction (transposed weights)

typedef __attribute__((ext_vector_type(8))) short short8;   // 8 bf16 = 4 VGPRs
typedef __attribute__((ext_vector_type(4))) float f32x4;    // MFMA accumulator

__device__ __forceinline__ short f2bf(float v) {
    unsigned u = __float_as_uint(v);
    unsigned r = (u + 0x7fffu + ((u >> 16) & 1u)) >> 16;   // RNE
    return (short)r;
}
__device__ __forceinline__ float bf2f(short s) {
    return __uint_as_float(((unsigned)(unsigned short)s) << 16);
}

// ---------------------------------------------------------------------------
// x [b][ci][i][j][k] fp32  ->  xT [b][i][j][k][ci] bf16  (channel-last)
__global__ __launch_bounds__(256) void prep_x(const float* __restrict__ x,
                                              short* __restrict__ xT)
{
    __shared__ float tl[32][33];
    const int blk = blockIdx.x;
    const int b = blk >> 10;
    const int i = (blk >> 5) & 31;
    const int j = blk & 31;

    const int k  = threadIdx.x & 31;
    const int cq = threadIdx.x >> 5;
    #pragma unroll
    for (int t = 0; t < 4; ++t) {
        const int ci = cq * 4 + t;
        tl[ci][k] = x[(((b*NC + ci)*DD + i)*DD + j)*DD + k];
    }
    __syncthreads();
    const int ci2 = threadIdx.x & 31;
    const int kq  = threadIdx.x >> 5;
    const int base = ((b*DD + i)*DD + j)*DD*NC;
    #pragma unroll
    for (int t = 0; t < 4; ++t) {
        const int kk = kq * 4 + t;
        xT[base + kk*NC + ci2] = f2bf(tl[ci2][kk]);
    }
}

// ---------------------------------------------------------------------------
// Wh/Wz/Ws fp32 [dir][co][ci][27] -> Wt bf16 [dir][tap][g*32+co][ci]
__global__ __launch_bounds__(256) void prep_w(const float* __restrict__ Wh,
                                              const float* __restrict__ Wz,
                                              const float* __restrict__ Ws,
                                              short* __restrict__ Wt)
{
    const int idx = blockIdx.x * 256 + threadIdx.x;   // 8*27*96*32 = 663552 total
    if (idx >= 8*WT_DIR) return;
    const int ci  = idx & 31;
    const int n   = (idx >> 5) % 96;
    const int tap = (idx / (96*32)) % 27;
    const int dir = idx / WT_DIR;
    const int g   = n >> 5;
    const int co  = n & 31;
    const float* W = (g == 0) ? Wh : (g == 1) ? Wz : Ws;
    Wt[idx] = f2bf(W[dir*3*WDIR/3 + ((co*NC + ci)*27 + tap)] );
}

// ---------------------------------------------------------------------------
// MFMA conv: 27 shifted GEMMs over K=Cin=32.  Block = (b, i, 4 j's): M=128
// voxels x N=96 (3 gates x 32 co).  4 waves: (m-half) x (n-half).
__global__ __launch_bounds__(256) void conv_mfma(
    const short* __restrict__ xT, const short* __restrict__ Wt,
    const float* __restrict__ bh, const float* __restrict__ bz, const float* __restrict__ bs,
    short* __restrict__ outh, short* __restrict__ outz, short* __restrict__ outs)
{
    // A: 18 halo rows (3 ri x 6 jj) x 34 k x 32 ci bf16 = 39168 B
    __shared__ short As[18*34*32];
    // B: per-(ri,rj) group, 3 rk taps x 96 n x 32 ci bf16, double buffered = 36864 B
    __shared__ short Bs[2][3*96*32];

    const int tid  = threadIdx.x;
    const int lane = tid & 63;
    const int wave = tid >> 6;
    const int mh   = wave & 1;    // m-half: 4 m-tiles each (M=128 -> 8 tiles of 16)
    const int nh   = wave >> 1;   // n-half: 3 n-tiles each (N=96 -> 6 tiles of 16)
    const int lr   = lane & 15;
    const int lq   = lane >> 4;

    const int blk = blockIdx.x;           // 512 = 2 * 32 * 8
    const int b  = blk >> 8;
    const int i  = (blk >> 3) & 31;
    const int j0 = (blk & 7) * 4;

    // ---- stage A halo rows (interior as uint, zero the k ends) ----
    {
        unsigned* Au = (unsigned*)As;
        for (int t = tid; t < 18*512; t += 256) {
            const int row = t >> 9;
            const int e   = t & 511;
            const int ii = i  - 1 + row / 6;
            const int jj = j0 - 1 + row % 6;
            unsigned v = 0;
            if ((unsigned)ii < 32u && (unsigned)jj < 32u)
                v = ((const unsigned*)(xT + ((b*DD + ii)*DD + jj)*DD*NC))[e];
            Au[row*544 + 16 + e] = v;
        }
        for (int t = tid; t < 18*32; t += 256) {
            const int row = t >> 5;
            const int e   = t & 31;
            Au[row*544 + (e < 16 ? e : e - 16 + 528)] = 0;
        }
    }
    // ---- stage B group 0 ----
    {
        const unsigned* src = (const unsigned*)Wt;   // group g at uint offset g*4608
        unsigned* dst = (unsigned*)Bs[0];
        for (int t = tid; t < 4608; t += 256) dst[t] = src[t];
    }

    // ---- init accumulators with bias ----
    f32x4 acc[4][3];
    #pragma unroll
    for (int nt = 0; nt < 3; ++nt) {
        const int n = (nh*3 + nt)*16 + lr;
        const int g = n >> 5, co = n & 31;
        const float bv = (g == 0) ? bh[co] : (g == 1) ? bz[co] : bs[co];
        #pragma unroll
        for (int mt = 0; mt < 4; ++mt) {
            acc[mt][nt][0] = bv; acc[mt][nt][1] = bv;
            acc[mt][nt][2] = bv; acc[mt][nt][3] = bv;
        }
    }
    __syncthreads();

    // ---- main loop: 9 (ri,rj) groups x 3 rk taps ----
    for (int g = 0; g < 9; ++g) {
        const int cur = g & 1;
        if (g < 8) {
            const unsigned* src = (const unsigned*)Wt + (g + 1)*4608;
            unsigned* dst = (unsigned*)Bs[cur ^ 1];
            for (int t = tid; t < 4608; t += 256) dst[t] = src[t];
        }
        const int ri = g / 3;
        const int rj = g - 3*ri;
        #pragma unroll
        for (int rk = 0; rk < 3; ++rk) {
            short8 af[4];
            #pragma unroll
            for (int mt = 0; mt < 4; ++mt) {
                const int mg = (mh*4 + mt)*16 + lr;     // voxel within M=128
                const int jd = mg >> 5, kv = mg & 31;
                const int row = ri*6 + jd + rj;
                af[mt] = *(const short8*)&As[(row*34 + kv + rk)*32 + lq*8];
            }
            short8 bf_[3];
            #pragma unroll
            for (int nt = 0; nt < 3; ++nt) {
                const int nl = (nh*3 + nt)*16 + lr;
                bf_[nt] = *(const short8*)&Bs[cur][(rk*96 + nl)*32 + lq*8];
            }
            #pragma unroll
            for (int mt = 0; mt < 4; ++mt)
                #pragma unroll
                for (int nt = 0; nt < 3; ++nt)
                    acc[mt][nt] = __builtin_amdgcn_mfma_f32_16x16x32_bf16(
                        af[mt], bf_[nt], acc[mt][nt], 0, 0, 0);
        }
        __syncthreads();
    }

    // ---- epilogue: C/D layout col=lane&15, row=(lane>>4)*4+reg ----
    #pragma unroll
    for (int nt = 0; nt < 3; ++nt) {
        const int n = (nh*3 + nt)*16 + lr;
        const int g = n >> 5, co = n & 31;
        short* dst = (g == 0) ? outh : (g == 1) ? outz : outs;
        #pragma unroll
        for (int mt = 0; mt < 4; ++mt) {
            #pragma unroll
            for (int r = 0; r < 4; ++r) {
                const int m = (mh*4 + mt)*16 + lq*4 + r;
                const int jd = m >> 5, kv = m & 31;
                float v = acc[mt][nt][r];
                if (g != 0) v = 1.0f / (1.0f + expf(-v));
                dst[(((b*DD + i)*DD + (j0 + jd))*DD + kv)*NC + co] = f2bf(v);
            }
        }
    }
}

// ---------------------------------------------------------------------------
// Diagonal GRU scan for direction (di,dj,dk), accumulating o*s into acc (fp32).
// Chains partition the volume; lane = channel. 2977 chains per batch.
__global__ __launch_bounds__(256) void gru_scan(
    const short* __restrict__ bufh, const short* __restrict__ bufz,
    const short* __restrict__ bufs, float* __restrict__ acc,
    const float* __restrict__ h0, int di, int dj, int dk)
{
    const int c    = threadIdx.x & 31;
    const int slot = threadIdx.x >> 5;
    const int cid  = blockIdx.x * 8 + slot;
    if (cid >= 2977) return;
    const int b = blockIdx.y;

    int ic, jc, kc;
    if (cid < 1024)      { ic = 0;             jc = cid >> 5;      kc = cid & 31; }
    else if (cid < 2016) { int t = cid - 1024; ic = 1 + (t >> 5);  jc = 0; kc = t & 31; }
    else                 { int t = cid - 2016; int q = t / 31;
                           ic = 1 + q;         jc = 1 + (t - q*31); kc = 0; }

    int mx = ic > jc ? ic : jc; if (kc > mx) mx = kc;
    const int L  = 32 - mx;
    const int i0 = (di > 0) ? ic : 31 - ic;
    const int j0 = (dj > 0) ? jc : 31 - jc;
    const int k0 = (dk > 0) ? kc : 31 - kc;
    const int step = di*(DD*DD*NC) + dj*(DD*NC) + dk*NC;

    int p = b*(VOL*NC) + i0*(DD*DD*NC) + j0*(DD*NC) + k0*NC + c;
    float prev = h0[c];
    for (int s = 0; s < L; ++s) {
        const float zv = bf2f(bufz[p]);
        const float hv = bf2f(bufh[p]);
        const float sv = bf2f(bufs[p]);
        const float o  = zv*hv + (1.0f - zv)*prev;
        acc[p] += o * sv;
        prev = o;
        p += step;
    }
}

// ---------------------------------------------------------------------------
// (b,i,j,k,c) fp32 -> (b,c,i,j,k) transpose into d_out.
__global__ __launch_bounds__(256) void transpose_out(
    const float* __restrict__ acc, float* __restrict__ out)
{
    __shared__ float tl[32][33];
    const int blk = blockIdx.x;
    const int b = blk >> 10;
    const int i = (blk >> 5) & 31;
    const int j = blk & 31;

    const int c  = threadIdx.x & 31;
    const int kq = threadIdx.x >> 5;
    const int base = ((b*DD + i)*DD + j)*DD*NC;
    #pragma unroll
    for (int t = 0; t < 4; ++t) {
        const int k = kq*4 + t;
        tl[k][c] = acc[base + k*NC + c];
    }
    __syncthreads();

    const int k2 = threadIdx.x & 31;
    const int cq = threadIdx.x >> 5;
    const int obase = b*(NC*VOL) + i*(DD*DD) + j*DD;
    #pragma unroll
    for (int t = 0; t < 4; ++t) {
        const int co = cq*4 + t;
        out[obase + co*VOL + k2] = tl[k2][co];
    }
}

// ---------------------------------------------------------------------------
extern "C" void kernel_launch(void* const* d_in, const int* in_sizes, int n_in,
                              void* d_out, int out_size, void* d_ws, size_t ws_size,
                              hipStream_t stream)
{
    const float* x  = (const float*)d_in[0];
    const float* Wh = (const float*)d_in[1];
    const float* bh = (const float*)d_in[2];
    const float* Wz = (const float*)d_in[3];
    const float* bz = (const float*)d_in[4];
    const float* Ws = (const float*)d_in[5];
    const float* bs = (const float*)d_in[6];
    const float* h0 = (const float*)d_in[7];
    float* out = (float*)d_out;

    // Workspace layout (25.3 MB total):
    float* acc  = (float*)d_ws;                        // 8 MB fp32 channel-last
    short* bufh = (short*)(acc + BUF_ELEMS);           // 4 MB bf16
    short* bufz = bufh + BUF_ELEMS;                    // 4 MB
    short* bufs = bufz + BUF_ELEMS;                    // 4 MB
    short* xT   = bufs + BUF_ELEMS;                    // 4 MB bf16 channel-last x
    short* Wt   = xT + BUF_ELEMS;                      // 1.27 MB bf16 weights

    prep_x<<<NB*DD*DD, 256, 0, stream>>>(x, xT);
    prep_w<<<(8*WT_DIR + 255)/256, 256, 0, stream>>>(Wh, Wz, Ws, Wt);
    hipMemsetAsync(acc, 0, BUF_ELEMS*sizeof(float), stream);

    for (int n = 0; n < 8; ++n) {
        const int di = (n & 4) ? 1 : -1;
        const int dj = (n & 2) ? 1 : -1;
        const int dk = (n & 1) ? 1 : -1;
        conv_mfma<<<NB*DD*8, 256, 0, stream>>>(
            xT, Wt + n*WT_DIR,
            bh + n*NC, bz + n*NC, bs + n*NC,
            bufh, bufz, bufs);
        gru_scan<<<dim3((2977 + 7)/8, NB), 256, 0, stream>>>(
            bufh, bufz, bufs, acc, h0 + n*NC, di, dj, dk);
    }
    transpose_out<<<NB*DD*DD, 256, 0, stream>>>(acc, out);
}

// Round 3
// 387.089 us; speedup vs baseline: 10.1111x; 1.2770x over previous
//
#include <hip/hip_runtime.h>
#include <hip/hip_bf16.h>
#include <math.h>

// Problem constants: B=2, Cin=Cout=32, D=H=W=32, 3x3x3 conv pad 1, 8 directions.
#define NB 2
#define NC 32
#define DD 32
#define VOL (DD*DD*DD)            // 32768
#define WDIR (NC*NC*27)           // 27648 floats per direction per gate
#define BUF_ELEMS (NB*VOL*NC)     // 2097152 elements per channel-last buffer
#define WT_DIR (27*96*32)         // 82944 bf16 per direction (transposed weights)

typedef __attribute__((ext_vector_type(8))) short short8;   // 8 bf16 = 4 VGPRs
typedef __attribute__((ext_vector_type(4))) float f32x4;    // MFMA accumulator

__device__ __forceinline__ short f2bf(float v) {
    unsigned u = __float_as_uint(v);
    unsigned r = (u + 0x7fffu + ((u >> 16) & 1u)) >> 16;   // RNE
    return (short)r;
}
__device__ __forceinline__ float bf2f(short s) {
    return __uint_as_float(((unsigned)(unsigned short)s) << 16);
}

// async global->LDS, 16 B per lane; gptr per-lane, lds dest = uniform base + lane*16
__device__ __forceinline__ void async_copy16(const void* g, void* l) {
    __builtin_amdgcn_global_load_lds(
        (const __attribute__((address_space(1))) unsigned*)g,
        (__attribute__((address_space(3))) unsigned*)l, 16, 0, 0);
}

// ---------------------------------------------------------------------------
// x [b][ci][i][j][k] fp32  ->  xT [b][i][j][k][ci] bf16  (channel-last)
__global__ __launch_bounds__(256) void prep_x(const float* __restrict__ x,
                                              short* __restrict__ xT)
{
    __shared__ float tl[32][33];
    const int blk = blockIdx.x;
    const int b = blk >> 10;
    const int i = (blk >> 5) & 31;
    const int j = blk & 31;

    const int k  = threadIdx.x & 31;
    const int cq = threadIdx.x >> 5;
    #pragma unroll
    for (int t = 0; t < 4; ++t) {
        const int ci = cq * 4 + t;
        tl[ci][k] = x[(((b*NC + ci)*DD + i)*DD + j)*DD + k];
    }
    __syncthreads();
    const int ci2 = threadIdx.x & 31;
    const int kq  = threadIdx.x >> 5;
    const int base = ((b*DD + i)*DD + j)*DD*NC;
    #pragma unroll
    for (int t = 0; t < 4; ++t) {
        const int kk = kq * 4 + t;
        xT[base + kk*NC + ci2] = f2bf(tl[ci2][kk]);
    }
}

// ---------------------------------------------------------------------------
// Wh/Wz/Ws fp32 [dir][co][ci][27] -> Wt bf16 [dir][tap][g*32+co][ci]
__global__ __launch_bounds__(256) void prep_w(const float* __restrict__ Wh,
                                              const float* __restrict__ Wz,
                                              const float* __restrict__ Ws,
                                              short* __restrict__ Wt)
{
    const int idx = blockIdx.x * 256 + threadIdx.x;   // 8*27*96*32 = 663552 total
    if (idx >= 8*WT_DIR) return;
    const int ci  = idx & 31;
    const int n   = (idx >> 5) % 96;
    const int tap = (idx / (96*32)) % 27;
    const int dir = idx / WT_DIR;
    const int g   = n >> 5;
    const int co  = n & 31;
    const float* W = (g == 0) ? Wh : (g == 1) ? Wz : Ws;
    Wt[idx] = f2bf(W[dir*WDIR + (co*NC + ci)*27 + tap]);
}

// ---------------------------------------------------------------------------
// MFMA conv: 27 shifted GEMMs over K=Cin=32.
// Block = (b, i, 8 j's): M=256 voxels x N=96 (3 gates x 32 co).
// 4 waves = 2 m-halves x 2 n-halves; per wave 8 m-tiles x 3 n-tiles.
// As rows: (ii-rel 0..2) x (jj-rel 0..9), each row = 34 k-slots x 32 ci bf16.
__global__ __launch_bounds__(256, 1) void conv_mfma(
    const short* __restrict__ xT, const short* __restrict__ Wt,
    const float* __restrict__ bh, const float* __restrict__ bz, const float* __restrict__ bs,
    short* __restrict__ outh, short* __restrict__ outz, short* __restrict__ outs)
{
    __shared__ __align__(16) short As[30*34*32];     // 65,280 B
    __shared__ __align__(16) short Bs[2][3*96*32];   // 2 x 18,432 B

    const int tid  = threadIdx.x;
    const int lane = tid & 63;
    const int wave = tid >> 6;
    const int mh   = wave & 1;    // m-half: 8 m-tiles each (M=256 -> 16 tiles)
    const int nh   = wave >> 1;   // n-half: 3 n-tiles each (N=96 -> 6 tiles)
    const int lr   = lane & 15;
    const int lq   = lane >> 4;

    const int blk = blockIdx.x;   // 256 = 2 * 32 * 4
    const int b  = blk >> 7;
    const int i  = (blk >> 2) & 31;
    const int j0 = (blk & 3) * 8;

    // ---- zero the k-edge slots (kvr=0 and kvr=33) of all 30 rows ----
    if (tid < 240) {
        const int row = tid >> 3;
        const int e   = tid & 7;
        const int off = row*2176 + (e < 4 ? e*16 : 2112 + (e - 4)*16);
        *(short8*)((char*)As + off) = short8{};
    }
    // ---- stage A interior rows async (or zero invalid halo rows) ----
    for (int t = wave; t < 60; t += 4) {            // 30 rows x 2 KB halves
        const int row  = t >> 1;
        const int half = t & 1;
        const int rr = row / 10, jc = row - rr*10;
        const int ii = i + rr - 1, jj = j0 + jc - 1;
        char* ldst = (char*)As + row*2176 + 64 + half*1024 + lane*16;
        if ((unsigned)ii < 32u && (unsigned)jj < 32u) {
            const char* g = (const char*)(xT + ((b*DD + ii)*DD + jj)*DD*NC)
                            + half*1024 + lane*16;
            async_copy16(g, ldst);
        } else {
            *(short8*)ldst = short8{};
        }
    }
    // ---- stage B group 0 async (18,432 B) ----
    for (int t = wave; t < 18; t += 4)
        async_copy16((const char*)Wt + t*1024 + lane*16,
                     (char*)Bs[0] + t*1024 + lane*16);

    // ---- init accumulators with bias ----
    f32x4 acc[8][3];
    #pragma unroll
    for (int nt = 0; nt < 3; ++nt) {
        const int n = nh*48 + nt*16 + lr;
        const int gg = n >> 5, co = n & 31;
        const float bv = (gg == 0) ? bh[co] : (gg == 1) ? bz[co] : bs[co];
        #pragma unroll
        for (int mt = 0; mt < 8; ++mt)
            acc[mt][nt] = (f32x4){bv, bv, bv, bv};
    }
    __syncthreads();

    // ---- main loop: 9 (ri,rj) groups x 3 rk taps ----
    for (int g9 = 0; g9 < 9; ++g9) {
        const int cur = g9 & 1;
        if (g9 < 8) {
            const char* src = (const char*)(Wt + (g9 + 1)*9216);
            char* dstb = (char*)Bs[cur ^ 1];
            for (int t = wave; t < 18; t += 4)
                async_copy16(src + t*1024 + lane*16, dstb + t*1024 + lane*16);
        }
        const int ri = g9 / 3;
        const int rj = g9 - 3*ri;
        const int rowb = (ri*10 + mh*4 + rj) * 1088;   // base row for this wave

        #pragma unroll
        for (int rk = 0; rk < 3; ++rk) {
            short8 bfr[3];
            #pragma unroll
            for (int nt = 0; nt < 3; ++nt)
                bfr[nt] = *(const short8*)&Bs[cur][(rk*96 + nh*48 + nt*16 + lr)*32 + lq*8];
            short8 afr[8];
            #pragma unroll
            for (int mt = 0; mt < 8; ++mt) {
                const int jd  = mt >> 1;
                const int kvr = (mt & 1)*16 + lr + rk;
                afr[mt] = *(const short8*)&As[rowb + jd*1088 + kvr*32 + lq*8];
            }
            #pragma unroll
            for (int mt = 0; mt < 8; ++mt)
                #pragma unroll
                for (int nt = 0; nt < 3; ++nt)
                    acc[mt][nt] = __builtin_amdgcn_mfma_f32_16x16x32_bf16(
                        afr[mt], bfr[nt], acc[mt][nt], 0, 0, 0);
        }
        __syncthreads();
    }

    // ---- epilogue: C/D layout col(lr)=n, row(lq*4+r)=m ----
    #pragma unroll
    for (int nt = 0; nt < 3; ++nt) {
        const int n = nh*48 + nt*16 + lr;
        const int gg = n >> 5, co = n & 31;
        short* dst = (gg == 0) ? outh : (gg == 1) ? outz : outs;
        #pragma unroll
        for (int mt = 0; mt < 8; ++mt) {
            #pragma unroll
            for (int r = 0; r < 4; ++r) {
                const int m  = mh*128 + mt*16 + lq*4 + r;
                const int jd = m >> 5, kv = m & 31;
                float v = acc[mt][nt][r];
                if (gg != 0) v = 1.0f / (1.0f + __expf(-v));
                dst[(((b*DD + i)*DD + (j0 + jd))*DD + kv)*NC + co] = f2bf(v);
            }
        }
    }
}

// ---------------------------------------------------------------------------
// Diagonal GRU scan for direction (di,dj,dk), accumulating o*s into acc (fp32).
// Chains partition the volume; lane = channel. 2977 chains per batch.
__global__ __launch_bounds__(256) void gru_scan(
    const short* __restrict__ bufh, const short* __restrict__ bufz,
    const short* __restrict__ bufs, float* __restrict__ acc,
    const float* __restrict__ h0, int di, int dj, int dk)
{
    const int c    = threadIdx.x & 31;
    const int slot = threadIdx.x >> 5;
    const int cid  = blockIdx.x * 8 + slot;
    if (cid >= 2977) return;
    const int b = blockIdx.y;

    int ic, jc, kc;
    if (cid < 1024)      { ic = 0;             jc = cid >> 5;      kc = cid & 31; }
    else if (cid < 2016) { int t = cid - 1024; ic = 1 + (t >> 5);  jc = 0; kc = t & 31; }
    else                 { int t = cid - 2016; int q = t / 31;
                           ic = 1 + q;         jc = 1 + (t - q*31); kc = 0; }

    int mx = ic > jc ? ic : jc; if (kc > mx) mx = kc;
    const int L  = 32 - mx;
    const int i0 = (di > 0) ? ic : 31 - ic;
    const int j0 = (dj > 0) ? jc : 31 - jc;
    const int k0 = (dk > 0) ? kc : 31 - kc;
    const int step = di*(DD*DD*NC) + dj*(DD*NC) + dk*NC;

    int p = b*(VOL*NC) + i0*(DD*DD*NC) + j0*(DD*NC) + k0*NC + c;
    float prev = h0[c];
    for (int s = 0; s < L; ++s) {
        const float zv = bf2f(bufz[p]);
        const float hv = bf2f(bufh[p]);
        const float sv = bf2f(bufs[p]);
        const float o  = zv*hv + (1.0f - zv)*prev;
        acc[p] += o * sv;
        prev = o;
        p += step;
    }
}

// ---------------------------------------------------------------------------
// (b,i,j,k,c) fp32 -> (b,c,i,j,k) transpose into d_out.
__global__ __launch_bounds__(256) void transpose_out(
    const float* __restrict__ acc, float* __restrict__ out)
{
    __shared__ float tl[32][33];
    const int blk = blockIdx.x;
    const int b = blk >> 10;
    const int i = (blk >> 5) & 31;
    const int j = blk & 31;

    const int c  = threadIdx.x & 31;
    const int kq = threadIdx.x >> 5;
    const int base = ((b*DD + i)*DD + j)*DD*NC;
    #pragma unroll
    for (int t = 0; t < 4; ++t) {
        const int k = kq*4 + t;
        tl[k][c] = acc[base + k*NC + c];
    }
    __syncthreads();

    const int k2 = threadIdx.x & 31;
    const int cq = threadIdx.x >> 5;
    const int obase = b*(NC*VOL) + i*(DD*DD) + j*DD;
    #pragma unroll
    for (int t = 0; t < 4; ++t) {
        const int co = cq*4 + t;
        out[obase + co*VOL + k2] = tl[k2][co];
    }
}

// ---------------------------------------------------------------------------
extern "C" void kernel_launch(void* const* d_in, const int* in_sizes, int n_in,
                              void* d_out, int out_size, void* d_ws, size_t ws_size,
                              hipStream_t stream)
{
    const float* x  = (const float*)d_in[0];
    const float* Wh = (const float*)d_in[1];
    const float* bh = (const float*)d_in[2];
    const float* Wz = (const float*)d_in[3];
    const float* bz = (const float*)d_in[4];
    const float* Ws = (const float*)d_in[5];
    const float* bs = (const float*)d_in[6];
    const float* h0 = (const float*)d_in[7];
    float* out = (float*)d_out;

    // Workspace layout (25.3 MB total):
    float* acc  = (float*)d_ws;                        // 8 MB fp32 channel-last
    short* bufh = (short*)(acc + BUF_ELEMS);           // 4 MB bf16
    short* bufz = bufh + BUF_ELEMS;                    // 4 MB
    short* bufs = bufz + BUF_ELEMS;                    // 4 MB
    short* xT   = bufs + BUF_ELEMS;                    // 4 MB bf16 channel-last x
    short* Wt   = xT + BUF_ELEMS;                      // 1.27 MB bf16 weights

    prep_x<<<NB*DD*DD, 256, 0, stream>>>(x, xT);
    prep_w<<<(8*WT_DIR + 255)/256, 256, 0, stream>>>(Wh, Wz, Ws, Wt);
    hipMemsetAsync(acc, 0, BUF_ELEMS*sizeof(float), stream);

    for (int n = 0; n < 8; ++n) {
        const int di = (n & 4) ? 1 : -1;
        const int dj = (n & 2) ? 1 : -1;
        const int dk = (n & 1) ? 1 : -1;
        conv_mfma<<<NB*DD*4, 256, 0, stream>>>(
            xT, Wt + n*WT_DIR,
            bh + n*NC, bz + n*NC, bs + n*NC,
            bufh, bufz, bufs);
        gru_scan<<<dim3((2977 + 7)/8, NB), 256, 0, stream>>>(
            bufh, bufz, bufs, acc, h0 + n*NC, di, dj, dk);
    }
    transpose_out<<<NB*DD*DD, 256, 0, stream>>>(acc, out);
}